// Round 14
// baseline (196.732 us; speedup 1.0000x reference)
//
#include <hip/hip_runtime.h>
#include <math.h>

#define N_ATOMS 4096
#define F 128
#define K 8
#define KF 1024           // K*F
#define KFF 131072        // K*F*F
#define FF 16384          // F*F
#define NF 524288         // N*F
#define NKF 4194304       // N*K*F
#define MAXNB 128
#define RMAX 5.0f
#define GAMMA 2.56f       // (K/RMAX)^2
#define MU_STEP 0.714285714285714f  // RMAX/(K-1)
#define PI_F 3.14159265358979323846f
#define POR (PI_F / RMAX)
#define NCELL 6
#define NCELL3 216
#define CELLCAP 64
#define CINV 0.1739130434782609f   // NCELL/BOX

typedef __bf16 bf16x8_t __attribute__((ext_vector_type(8)));
typedef float f32x4_t __attribute__((ext_vector_type(4)));
typedef unsigned short u16x8_t __attribute__((ext_vector_type(8)));
typedef unsigned short u16x4_t __attribute__((ext_vector_type(4)));

__device__ __forceinline__ float sigm(float x){ return 1.0f/(1.0f + expf(-x)); }
__device__ __forceinline__ unsigned short f2bf(float x){
  unsigned int u = __float_as_uint(x);
  u += 0x7fff + ((u >> 16) & 1);
  return (unsigned short)(u >> 16);
}

// ======================= device bodies ======================================

__device__ __forceinline__ void agg_body(int a, int t,
        const float* __restrict__ h_in, const int* __restrict__ nb_idx,
        const float* __restrict__ rbf, const int* __restrict__ nb_cnt,
        unsigned short* __restrict__ Af){
  int grp = t >> 6, lane = t & 63;
  __shared__ int s_j[MAXNB];
  __shared__ float s_acc[4][8][128];
  int cnt = nb_cnt[a];
  for (int idx = t; idx < cnt; idx += 256) s_j[idx] = nb_idx[a*MAXNB + idx];
  __syncthreads();
  float2 acc[8];
  #pragma unroll
  for (int k = 0; k < 8; k++) acc[k] = {0.f, 0.f};
  const float4* rb = (const float4*)(rbf + (size_t)a*MAXNB*8);
  for (int n = grp; n < cnt; n += 4){
    float2 hv = *(const float2*)&h_in[(size_t)s_j[n]*F + lane*2];
    float4 r0 = rb[n*2], r1 = rb[n*2+1];
    acc[0].x += r0.x*hv.x; acc[0].y += r0.x*hv.y;
    acc[1].x += r0.y*hv.x; acc[1].y += r0.y*hv.y;
    acc[2].x += r0.z*hv.x; acc[2].y += r0.z*hv.y;
    acc[3].x += r0.w*hv.x; acc[3].y += r0.w*hv.y;
    acc[4].x += r1.x*hv.x; acc[4].y += r1.x*hv.y;
    acc[5].x += r1.y*hv.x; acc[5].y += r1.y*hv.y;
    acc[6].x += r1.z*hv.x; acc[6].y += r1.z*hv.y;
    acc[7].x += r1.w*hv.x; acc[7].y += r1.w*hv.y;
  }
  #pragma unroll
  for (int k = 0; k < 8; k++)
    *(float2*)&s_acc[grp][k][lane*2] = acc[k];
  __syncthreads();
  int k = t >> 5, q = t & 31;
  int f0 = q*4;
  float v[4];
  #pragma unroll
  for (int i = 0; i < 4; i++){
    int f = f0 + i;
    v[i] = s_acc[0][k][f] + s_acc[1][k][f] + s_acc[2][k][f] + s_acc[3][k][f];
  }
  int lf = (a & 15) | (((f0 >> 3) & 3) << 4);
  int kc = k*4 + (f0 >> 5);
  size_t flat = (size_t)(a >> 4)*16384 + ((size_t)kc*64 + lf)*8 + (f0 & 7);
  u16x4_t o;
  o[0] = f2bf(v[0]); o[1] = f2bf(v[1]); o[2] = f2bf(v[2]); o[3] = f2bf(v[3]);
  *(u16x4_t*)(Af + flat) = o;
}

__device__ __forceinline__ void mgemm_bwd_body(int bx, int t,
        const unsigned short* __restrict__ Gf, const unsigned short* __restrict__ Bf,
        unsigned short* __restrict__ dAbf){
  int l = t & 63, w = t >> 6;
  int rtile = (bx & 63)*4 + w;
  int nt0 = (bx >> 6)*8;
  f32x4_t acc[8];
  #pragma unroll
  for (int i = 0; i < 8; i++) acc[i] = (f32x4_t){0.f,0.f,0.f,0.f};
  const unsigned short* Ab = Gf + (size_t)rtile*2048 + l*8;
  const unsigned short* Bb = Bf + l*8;
  #pragma unroll
  for (int kc = 0; kc < 4; kc++){
    bf16x8_t a = *(const bf16x8_t*)(Ab + kc*512);
    #pragma unroll
    for (int nt = 0; nt < 8; nt++){
      bf16x8_t b = *(const bf16x8_t*)(Bb + (kc*64 + nt0 + nt)*512);
      acc[nt] = __builtin_amdgcn_mfma_f32_16x16x32_bf16(a, b, acc[nt], 0, 0, 0);
    }
  }
  int row0 = rtile*16 + (l >> 4)*4;
  int col = l & 15;
  #pragma unroll
  for (int nt = 0; nt < 8; nt++){
    #pragma unroll
    for (int r = 0; r < 4; r++)
      dAbf[(size_t)(row0+r)*1024 + (nt0+nt)*16 + col] = f2bf(acc[nt][r]);
  }
}

// ======================= kernels ============================================

// ---- prep: [0,16) cell binning; [16,80) wprep; [80,...) embed --------------
__global__ __launch_bounds__(256) void k_prep(const float* __restrict__ pos,
        const int* __restrict__ z, const float* __restrict__ embed,
        const float* __restrict__ W1, const float* __restrict__ W2,
        const float* __restrict__ Wr1,
        int* __restrict__ cell_cnt, int* __restrict__ cell_list,
        unsigned short* __restrict__ WF1, unsigned short* __restrict__ WF2,
        unsigned short* __restrict__ WDF2, unsigned short* __restrict__ WTF1,
        unsigned short* __restrict__ WTF2, unsigned short* __restrict__ Wr1F,
        unsigned short* __restrict__ Wr1TF,
        float* __restrict__ h0, unsigned short* __restrict__ h0bf){
  int t = threadIdx.x;
  if (blockIdx.x < 16){
    int i = blockIdx.x*256 + t;
    float x = pos[3*i], y = pos[3*i+1], zz = pos[3*i+2];
    int cx = (int)(x*CINV); cx = cx > 5 ? 5 : (cx < 0 ? 0 : cx);
    int cy = (int)(y*CINV); cy = cy > 5 ? 5 : (cy < 0 ? 0 : cy);
    int cz = (int)(zz*CINV); cz = cz > 5 ? 5 : (cz < 0 ? 0 : cz);
    int c = (cz*NCELL + cy)*NCELL + cx;
    int slot = atomicAdd(&cell_cnt[c], 1);
    if (slot < CELLCAP) cell_list[c*CELLCAP + slot] = i;
    return;
  }
  if (blockIdx.x >= 80){
    int idx = (blockIdx.x - 80)*256 + t;
    int i = idx >> 7, f = idx & 127;
    float v = embed[z[i]*F + f];
    h0[idx] = v;
    h0bf[idx] = f2bf(v);
    return;
  }
  int idx = (blockIdx.x - 16)*256 + t;   // 0..16383
  int l = idx & 63;
  int hi = idx >> 6;
  {
    int kc = hi >> 3, nt = hi & 7;
    int kfb = kc*32 + ((l>>4)&3)*8;
    int g = nt*16 + (l&15);
    u16x8_t v1, v2, vd;
    #pragma unroll
    for (int j = 0; j < 8; j++){
      int kf = kfb + j;
      v1[j] = f2bf(W1[kf*128 + g]);
      v2[j] = f2bf(W2[kf*128 + g]);
      vd[j] = f2bf(W2[(kf>>7)*FF + g*F + (kf&127)]);
    }
    *(u16x8_t*)(WF1 + idx*8) = v1;
    *(u16x8_t*)(WF2 + idx*8) = v2;
    *(u16x8_t*)(WDF2 + idx*8) = vd;
  }
  {
    int kc = hi >> 6, nt = hi & 63;
    int gb = kc*32 + ((l>>4)&3)*8;
    int kf = nt*16 + (l&15);
    u16x8_t t1, t2;
    #pragma unroll
    for (int j = 0; j < 8; j++){
      int g = gb + j;
      t1[j] = f2bf(W1[kf*128 + g]);
      t2[j] = f2bf(W2[kf*128 + g]);
    }
    *(u16x8_t*)(WTF1 + idx*8) = t1;
    *(u16x8_t*)(WTF2 + idx*8) = t2;
  }
  {
    int m = idx >> 9;
    int ll = (idx >> 3) & 63;
    int j = idx & 7;
    int kc = m >> 3, nt = m & 7;
    int kf = kc*32 + ((ll>>4)&3)*8 + j;
    int g = nt*16 + (ll&15);
    Wr1F[idx]  = f2bf(Wr1[kf*128 + g]);
    Wr1TF[idx] = f2bf(Wr1[g*128 + kf]);
  }
}

// ---- cell-list neighbor scan: 1 wave/atom, sort by j, fused rbf tail -------
__global__ __launch_bounds__(64) void k_nbscan(const float* __restrict__ pos,
        const int* __restrict__ cell_cnt, const int* __restrict__ cell_list,
        int* __restrict__ nb_idx, float* __restrict__ nb_d, int* __restrict__ nb_cnt,
        float* __restrict__ rbf, float* __restrict__ drbf){
  int a = blockIdx.x;
  int lane = threadIdx.x;
  __shared__ int s_jb[128];
  __shared__ float s_db[128];
  float pax = pos[3*a], pay = pos[3*a+1], paz = pos[3*a+2];
  int cx = (int)(pax*CINV); cx = cx > 5 ? 5 : (cx < 0 ? 0 : cx);
  int cy = (int)(pay*CINV); cy = cy > 5 ? 5 : (cy < 0 ? 0 : cy);
  int cz = (int)(paz*CINV); cz = cz > 5 ? 5 : (cz < 0 ? 0 : cz);
  int cnt = 0;
  for (int dz = -1; dz <= 1; dz++){
    int zc = cz + dz; if (zc < 0 || zc >= NCELL) continue;
    for (int dy = -1; dy <= 1; dy++){
      int yc = cy + dy; if (yc < 0 || yc >= NCELL) continue;
      for (int dx = -1; dx <= 1; dx++){
        int xc = cx + dx; if (xc < 0 || xc >= NCELL) continue;
        int c = (zc*NCELL + yc)*NCELL + xc;
        int m = cell_cnt[c];
        if (m > CELLCAP) m = CELLCAP;
        for (int base = 0; base < m; base += 64){
          int idx = base + lane;
          int j = -1; float d = 0.f; bool pred = false;
          if (idx < m){
            j = cell_list[c*CELLCAP + idx];
            float dxp = pax - pos[3*j], dyp = pay - pos[3*j+1], dzp = paz - pos[3*j+2];
            float d2 = dxp*dxp + dyp*dyp + dzp*dzp;
            d = sqrtf(d2);
            pred = (j != a) && (d2 > 0.0f) && (d < RMAX);
          }
          unsigned long long mm = __ballot(pred);
          int off = __popcll(mm & ((1ull << lane) - 1ull));
          if (pred && (cnt + off) < 128){ s_jb[cnt+off] = j; s_db[cnt+off] = d; }
          cnt += __popcll(mm);
        }
      }
    }
  }
  if (cnt > MAXNB) cnt = MAXNB;
  // pad
  for (int s = cnt + lane; s < 128; s += 64){ s_jb[s] = 0x7fffffff; s_db[s] = 1e9f; }
  __syncthreads();
  // bitonic sort ascending by j over 128 slots
  for (int k = 2; k <= 128; k <<= 1){
    for (int jj = k >> 1; jj > 0; jj >>= 1){
      #pragma unroll
      for (int sbase = 0; sbase < 128; sbase += 64){
        int s = sbase + lane;
        int partner = s ^ jj;
        if (partner > s){
          bool up = (s & k) == 0;
          int j1 = s_jb[s], j2 = s_jb[partner];
          bool sw = up ? (j1 > j2) : (j1 < j2);
          if (sw){
            float d1 = s_db[s], d2v = s_db[partner];
            s_jb[s] = j2; s_jb[partner] = j1;
            s_db[s] = d2v; s_db[partner] = d1;
          }
        }
      }
      __syncthreads();
    }
  }
  if (lane == 0) nb_cnt[a] = cnt;
  for (int n = lane; n < cnt; n += 64){
    nb_idx[a*MAXNB + n] = s_jb[n];
    nb_d[a*MAXNB + n]  = s_db[n];
    float d = s_db[n];
    float ph = POR*d;
    float cph, sph;
    __sincosf(ph, &sph, &cph);
    float env = 0.5f*(cph + 1.0f);
    float denv = -0.5f*POR*sph;
    float rr[8], dd[8];
    #pragma unroll
    for (int k = 0; k < 8; k++){
      float dm = d - MU_STEP*(float)k;
      float G = expf(-GAMMA*dm*dm);
      rr[k] = G*env;
      dd[k] = G*(-2.0f*GAMMA*dm*env + denv);
    }
    float4* rb = (float4*)(rbf + ((size_t)a*MAXNB + n)*8);
    rb[0] = {rr[0],rr[1],rr[2],rr[3]};
    rb[1] = {rr[4],rr[5],rr[6],rr[7]};
    float4* db = (float4*)(drbf + ((size_t)a*MAXNB + n)*8);
    db[0] = {dd[0],dd[1],dd[2],dd[3]};
    db[1] = {dd[4],dd[5],dd[6],dd[7]};
  }
}

// ---- standalone agg --------------------------------------------------------
__global__ __launch_bounds__(256) void k_agg(const float* __restrict__ h_in,
        const int* __restrict__ nb_idx, const float* __restrict__ rbf,
        const int* __restrict__ nb_cnt, unsigned short* __restrict__ Af){
  agg_body(blockIdx.x, threadIdx.x, h_in, nb_idx, rbf, nb_cnt, Af);
}

// ---- merged: [0,512) mgemm_bwd(dA2); [512, 4608) agg(g2) -------------------
__global__ __launch_bounds__(256) void k_bwdmix(const unsigned short* __restrict__ Gf,
        const unsigned short* __restrict__ Bf, unsigned short* __restrict__ dAbf,
        const float* __restrict__ g2b, const int* __restrict__ nb_idx,
        const float* __restrict__ rbf, const int* __restrict__ nb_cnt,
        unsigned short* __restrict__ Af){
  if (blockIdx.x < 512){
    mgemm_bwd_body(blockIdx.x, threadIdx.x, Gf, Bf, dAbf);
    return;
  }
  agg_body(blockIdx.x - 512, threadIdx.x, g2b, nb_idx, rbf, nb_cnt, Af);
}

// ---- standalone mgemm_bwd --------------------------------------------------
__global__ __launch_bounds__(256) void k_mgemm_bwd(const unsigned short* __restrict__ Gf,
        const unsigned short* __restrict__ Bf, unsigned short* __restrict__ dAbf){
  mgemm_bwd_body(blockIdx.x, threadIdx.x, Gf, Bf, dAbf);
}

// ---- full-K MFMA GEMM fwd-shape + fused epilogue ---------------------------
__global__ __launch_bounds__(256) void k_mgemm_fwd(const unsigned short* __restrict__ Af,
        const unsigned short* __restrict__ Bf, const float* __restrict__ addv,
        const float* __restrict__ msrc, float* __restrict__ out_m,
        float* __restrict__ out_h, unsigned short* __restrict__ out_hbf,
        unsigned short* __restrict__ out_frag, int mode){
  int t = threadIdx.x;
  int l = t & 63, w = t >> 6;
  int rtile = blockIdx.x;
  int nt = blockIdx.y*4 + w;
  f32x4_t accA = (f32x4_t){0.f,0.f,0.f,0.f};
  f32x4_t accB = (f32x4_t){0.f,0.f,0.f,0.f};
  const unsigned short* Ab = Af + (size_t)rtile*16384 + l*8;
  const unsigned short* Bb = Bf + l*8;
  #pragma unroll
  for (int kc = 0; kc < 32; kc += 2){
    bf16x8_t a0 = *(const bf16x8_t*)(Ab + kc*512);
    bf16x8_t b0 = *(const bf16x8_t*)(Bb + (kc*8 + nt)*512);
    bf16x8_t a1 = *(const bf16x8_t*)(Ab + (kc+1)*512);
    bf16x8_t b1 = *(const bf16x8_t*)(Bb + ((kc+1)*8 + nt)*512);
    accA = __builtin_amdgcn_mfma_f32_16x16x32_bf16(a0, b0, accA, 0, 0, 0);
    accB = __builtin_amdgcn_mfma_f32_16x16x32_bf16(a1, b1, accB, 0, 0, 0);
  }
  f32x4_t acc = accA + accB;
  int row0 = rtile*16 + (l >> 4)*4;
  int col = nt*16 + (l & 15);
  if (mode == 0){
    #pragma unroll
    for (int r = 0; r < 4; r++){
      int i = row0 + r;
      float m = acc[r] + addv[(size_t)i*F + col];
      out_m[(size_t)i*F + col] = m;
      float h = m*sigm(m);
      out_h[(size_t)i*F + col] = h;
      out_hbf[(size_t)i*F + col] = f2bf(h);
    }
  } else {
    int kc2 = col >> 5;
    int lfr0 = (((col >> 3) & 3) << 4);
    int jj = col & 7;
    #pragma unroll
    for (int r = 0; r < 4; r++){
      int i = row0 + r;
      float mm = msrc[(size_t)i*F + col];
      float sg = sigm(mm);
      float gv = (acc[r] + addv[(size_t)i*F + col])*(sg*(1.f + mm*(1.f - sg)));
      int lfr = (i & 15) | lfr0;
      size_t flat = (((size_t)(i>>4)*4 + kc2)*64 + lfr)*8 + jj;
      out_frag[flat] = f2bf(gv);
    }
  }
}

// ------- MFMA readout: 1 wave = 16 atoms ------------------------------------
__global__ __launch_bounds__(64) void k_readout(const unsigned short* __restrict__ h2bf,
        const float* __restrict__ m2, const unsigned short* __restrict__ Wr1F,
        const unsigned short* __restrict__ Wr1TF, const float* __restrict__ Wr2,
        float* __restrict__ e_at, float* __restrict__ g2,
        unsigned short* __restrict__ g2frag){
  int a0 = blockIdx.x*16;
  int l = threadIdx.x;
  int rl = l & 15;
  __shared__ unsigned short sdu[16][136];
  f32x4_t acc[8];
  #pragma unroll
  for (int nt = 0; nt < 8; nt++) acc[nt] = (f32x4_t){0.f,0.f,0.f,0.f};
  #pragma unroll
  for (int kc = 0; kc < 4; kc++){
    bf16x8_t af = *(const bf16x8_t*)(h2bf + (size_t)(a0+rl)*F + kc*32 + ((l>>4)&3)*8);
    #pragma unroll
    for (int nt = 0; nt < 8; nt++){
      bf16x8_t bf = *(const bf16x8_t*)(Wr1F + ((kc*8+nt)*64 + l)*8);
      acc[nt] = __builtin_amdgcn_mfma_f32_16x16x32_bf16(af, bf, acc[nt], 0, 0, 0);
    }
  }
  float epart[4] = {0.f,0.f,0.f,0.f};
  #pragma unroll
  for (int nt = 0; nt < 8; nt++){
    float w2 = Wr2[nt*16 + rl];
    #pragma unroll
    for (int r = 0; r < 4; r++){
      float u = acc[nt][r];
      float sg = sigm(u);
      epart[r] += u*sg*w2;
      sdu[(l>>4)*4 + r][nt*16 + rl] = f2bf(w2*(sg*(1.f + u*(1.f - sg))));
    }
  }
  #pragma unroll
  for (int o = 1; o < 16; o <<= 1){
    #pragma unroll
    for (int r = 0; r < 4; r++) epart[r] += __shfl_xor(epart[r], o);
  }
  if (rl == 0){
    #pragma unroll
    for (int r = 0; r < 4; r++) e_at[a0 + (l>>4)*4 + r] = epart[r];
  }
  __syncthreads();
  f32x4_t acc2[8];
  #pragma unroll
  for (int nt = 0; nt < 8; nt++) acc2[nt] = (f32x4_t){0.f,0.f,0.f,0.f};
  #pragma unroll
  for (int kc = 0; kc < 4; kc++){
    bf16x8_t af = *(const bf16x8_t*)&sdu[rl][kc*32 + ((l>>4)&3)*8];
    #pragma unroll
    for (int nt = 0; nt < 8; nt++){
      bf16x8_t bf = *(const bf16x8_t*)(Wr1TF + ((kc*8+nt)*64 + l)*8);
      acc2[nt] = __builtin_amdgcn_mfma_f32_16x16x32_bf16(af, bf, acc2[nt], 0, 0, 0);
    }
  }
  #pragma unroll
  for (int nt = 0; nt < 8; nt++){
    int g = nt*16 + rl;
    int kc2 = g >> 5;
    int lfr0 = (((g >> 3) & 3) << 4);
    int jj = g & 7;
    #pragma unroll
    for (int r = 0; r < 4; r++){
      int a = a0 + (l>>4)*4 + r;
      float mm = m2[(size_t)a*F + g];
      float sg = sigm(mm);
      float gv = acc2[nt][r]*(sg*(1.f + mm*(1.f - sg)));
      g2[(size_t)a*F + g] = gv;
      int lfr = (a & 15) | lfr0;
      g2frag[(((size_t)(a>>4)*4 + kc2)*64 + lfr)*8 + jj] = f2bf(gv);
    }
  }
}

// ------- per-edge scalar via MFMA -------------------------------------------
__global__ __launch_bounds__(256) void k_edge(const unsigned short* __restrict__ dA2bf,
        const unsigned short* __restrict__ dA1bf, const unsigned short* __restrict__ h1bf,
        const unsigned short* __restrict__ h0bf, const float* __restrict__ drbf,
        const int* __restrict__ nb_idx, const int* __restrict__ nb_cnt,
        float* __restrict__ edge_s){
  int a = blockIdx.x;
  int t = threadIdx.x;
  int w = t >> 6, l = t & 63;
  __shared__ int s_j[MAXNB];
  int cnt = nb_cnt[a];
  for (int idx = t; idx < cnt; idx += 256) s_j[idx] = nb_idx[a*MAXNB + idx];
  int r = l & 15;
  int sel = (l >> 4) & 3;
  u16x8_t a2u[4], a1u[4];
  #pragma unroll
  for (int kc = 0; kc < 4; kc++){
    u16x8_t v2 = {0,0,0,0,0,0,0,0};
    u16x8_t v1 = {0,0,0,0,0,0,0,0};
    if (r < 8){
      v2 = *(const u16x8_t*)(dA2bf + (size_t)a*KF + r*F + kc*32 + sel*8);
      v1 = *(const u16x8_t*)(dA1bf + (size_t)a*KF + r*F + kc*32 + sel*8);
    }
    a2u[kc] = v2; a1u[kc] = v1;
  }
  __syncthreads();
  for (int n0 = w*16; n0 < cnt; n0 += 64){
    int nl = n0 + r;
    int nls = nl < cnt ? nl : cnt - 1;
    int j = s_j[nls];
    const unsigned short* h1p = h1bf + (size_t)j*F + sel*8;
    const unsigned short* h0p = h0bf + (size_t)j*F + sel*8;
    f32x4_t acc = (f32x4_t){0.f,0.f,0.f,0.f};
    #pragma unroll
    for (int kc = 0; kc < 4; kc++){
      bf16x8_t b = *(const bf16x8_t*)(h1p + kc*32);
      acc = __builtin_amdgcn_mfma_f32_16x16x32_bf16(*(const bf16x8_t*)&a2u[kc], b, acc, 0, 0, 0);
    }
    #pragma unroll
    for (int kc = 0; kc < 4; kc++){
      bf16x8_t b = *(const bf16x8_t*)(h0p + kc*32);
      acc = __builtin_amdgcn_mfma_f32_16x16x32_bf16(*(const bf16x8_t*)&a1u[kc], b, acc, 0, 0, 0);
    }
    int krow = (l >> 4) * 4;
    float part = 0.f;
    if (krow < 8){
      float4 dr = *(const float4*)(drbf + ((size_t)a*MAXNB + nls)*8 + krow);
      part = acc[0]*dr.x + acc[1]*dr.y + acc[2]*dr.z + acc[3]*dr.w;
    }
    part += __shfl_xor(part, 16);
    if (l < 16 && nl < cnt) edge_s[a*MAXNB + nl] = part;
  }
}

// ------- force + (block N_ATOMS) energy sum ---------------------------------
__global__ __launch_bounds__(64) void k_force(const float* __restrict__ pos,
        const int* __restrict__ nb_idx, const float* __restrict__ nb_d,
        const int* __restrict__ nb_cnt, const float* __restrict__ edge_s,
        const float* __restrict__ e_at, float* __restrict__ out){
  int a = blockIdx.x;
  int lane = threadIdx.x;
  if (a == N_ATOMS){
    float s = 0.f;
    for (int i = lane; i < N_ATOMS; i += 64) s += e_at[i];
    #pragma unroll
    for (int o = 1; o < 64; o <<= 1) s += __shfl_xor(s, o);
    if (lane == 0) out[0] = s;
    return;
  }
  float pax = pos[3*a], pay = pos[3*a+1], paz = pos[3*a+2];
  int cnt = nb_cnt[a];
  float fx = 0.f, fy = 0.f, fz = 0.f;
  for (int n = lane; n < cnt; n += 64){
    int j = nb_idx[a*MAXNB + n];
    float d = nb_d[a*MAXNB + n];
    float s = edge_s[a*MAXNB + n];
    int cj = nb_cnt[j];
    int lo = 0, hi = cj - 1, p = -1;
    while (lo <= hi){
      int mid = (lo + hi) >> 1;
      int v = nb_idx[j*MAXNB + mid];
      if (v == a){ p = mid; break; }
      if (v < a) lo = mid + 1; else hi = mid - 1;
    }
    float sj = (p >= 0) ? edge_s[j*MAXNB + p] : 0.0f;
    float coef = (s + sj)/d;
    float dx = pax - pos[3*j], dy = pay - pos[3*j+1], dz = paz - pos[3*j+2];
    fx -= coef*dx; fy -= coef*dy; fz -= coef*dz;
  }
  #pragma unroll
  for (int o = 1; o < 64; o <<= 1){
    fx += __shfl_xor(fx, o); fy += __shfl_xor(fy, o); fz += __shfl_xor(fz, o);
  }
  if (lane == 0){
    out[1 + 3*a + 0] = fx;
    out[1 + 3*a + 1] = fy;
    out[1 + 3*a + 2] = fz;
  }
}

extern "C" void kernel_launch(void* const* d_in, const int* in_sizes, int n_in,
                              void* d_out, int out_size, void* d_ws, size_t ws_size,
                              hipStream_t stream){
  const float* pos   = (const float*)d_in[0];
  const int*   z     = (const int*)  d_in[1];
  const float* embed = (const float*)d_in[2];
  const float* W1    = (const float*)d_in[3];
  const float* W2    = (const float*)d_in[4];
  const float* Wr1   = (const float*)d_in[5];
  const float* Wr2   = (const float*)d_in[6];
  float* out = (float*)d_out;

  float* ws = (float*)d_ws;
  float* h0   = ws;            // NF
  float* h1   = h0 + NF;
  float* h2   = h1 + NF;
  float* m1   = h2 + NF;
  float* m2   = m1 + NF;
  float* g2b  = m2 + NF;
  float* Bbuf = g2b + NF;      // NKF slot: dA2 bf16
  float* Cbuf = Bbuf + NKF;    // NKF slot: dA1 bf16
  unsigned short* dA2bf = (unsigned short*)Bbuf;
  unsigned short* dA1bf = (unsigned short*)Cbuf;
  unsigned short* Afrag = (unsigned short*)(Cbuf + NKF);  // NKF bf16
  unsigned short* Gfrag = Afrag + NKF;                    // NF bf16
  unsigned short* h0bf = Gfrag + NF;   // NF bf16
  unsigned short* h1bf = h0bf + NF;    // NF bf16
  unsigned short* h2bf = h1bf + NF;    // NF bf16
  unsigned short* WF1  = h2bf + NF;    // KFF bf16 each
  unsigned short* WF2  = WF1 + KFF;
  unsigned short* WDF2 = WF2 + KFF;
  unsigned short* WTF1 = WDF2 + KFF;
  unsigned short* WTF2 = WTF1 + KFF;
  unsigned short* Wr1F  = WTF2 + KFF;  // FF bf16
  unsigned short* Wr1TF = Wr1F + FF;   // FF bf16
  float* e_at = (float*)(Wr1TF + FF);  // N
  float* nb_d = e_at + N_ATOMS;        // N*MAXNB
  float* edge_s = nb_d + N_ATOMS*MAXNB;// N*MAXNB
  float* rbf  = edge_s + N_ATOMS*MAXNB;         // N*MAXNB*8
  float* drbf = rbf + N_ATOMS*MAXNB*8;          // N*MAXNB*8
  int* nb_idx = (int*)(drbf + N_ATOMS*MAXNB*8); // N*MAXNB
  int* nb_cnt = nb_idx + N_ATOMS*MAXNB;         // N
  int* cell_cnt = nb_cnt + N_ATOMS;             // NCELL3
  int* cell_list = cell_cnt + NCELL3;           // NCELL3*CELLCAP

  hipMemsetAsync(cell_cnt, 0, NCELL3*sizeof(int), stream);
  // prep: bin (16) | wprep (64) | embed (2048)
  k_prep<<<16 + 64 + NF/256, 256, 0, stream>>>(pos, z, embed, W1, W2, Wr1,
        cell_cnt, cell_list,
        WF1, WF2, WDF2, WTF1, WTF2, Wr1F, Wr1TF, h0, h0bf);
  k_nbscan<<<N_ATOMS, 64, 0, stream>>>(pos, cell_cnt, cell_list,
        nb_idx, nb_d, nb_cnt, rbf, drbf);

  // forward layer 1
  k_agg<<<N_ATOMS, 256, 0, stream>>>(h0, nb_idx, rbf, nb_cnt, Afrag);
  k_mgemm_fwd<<<dim3(256, 2), 256, 0, stream>>>(Afrag, WF1, h0, h0, m1, h1, h1bf, Gfrag, 0);
  // forward layer 2
  k_agg<<<N_ATOMS, 256, 0, stream>>>(h1, nb_idx, rbf, nb_cnt, Afrag);
  k_mgemm_fwd<<<dim3(256, 2), 256, 0, stream>>>(Afrag, WF2, h1, h1, m2, h2, h2bf, Gfrag, 0);

  // MFMA readout (writes e_at, g2 f32 + frag)
  k_readout<<<N_ATOMS/16, 64, 0, stream>>>(h2bf, m2, Wr1F, Wr1TF, Wr2, e_at, g2b, Gfrag);

  // backward: dA2 GEMM + Agg2 in one launch
  k_bwdmix<<<512 + N_ATOMS, 256, 0, stream>>>(Gfrag, WTF2, dA2bf,
        g2b, nb_idx, rbf, nb_cnt, Afrag);
  k_mgemm_fwd<<<dim3(256, 2), 256, 0, stream>>>(Afrag, WDF2, g2b, m1, m1, m1, h2bf, Gfrag, 1); // g1 -> Gfrag
  k_mgemm_bwd<<<512, 256, 0, stream>>>(Gfrag, WTF1, dA1bf);       // dA1
  k_edge<<<N_ATOMS, 256, 0, stream>>>(dA2bf, dA1bf, h1bf, h0bf, drbf, nb_idx, nb_cnt, edge_s);
  k_force<<<N_ATOMS + 1, 64, 0, stream>>>(pos, nb_idx, nb_d, nb_cnt, edge_s, e_at, out);
}

// Round 15
// 185.687 us; speedup vs baseline: 1.0595x; 1.0595x over previous
//
#include <hip/hip_runtime.h>
#include <math.h>

#define N_ATOMS 4096
#define F 128
#define K 8
#define KF 1024           // K*F
#define KFF 131072        // K*F*F
#define FF 16384          // F*F
#define NF 524288         // N*F
#define NKF 4194304       // N*K*F
#define MAXNB 128
#define RMAX 5.0f
#define RMAX2 25.0f
#define GAMMA 2.56f       // (K/RMAX)^2
#define MU_STEP 0.714285714285714f  // RMAX/(K-1)
#define PI_F 3.14159265358979323846f
#define POR (PI_F / RMAX)

typedef __bf16 bf16x8_t __attribute__((ext_vector_type(8)));
typedef float f32x4_t __attribute__((ext_vector_type(4)));
typedef unsigned short u16x8_t __attribute__((ext_vector_type(8)));
typedef unsigned short u16x4_t __attribute__((ext_vector_type(4)));

__device__ __forceinline__ float sigm(float x){ return 1.0f/(1.0f + expf(-x)); }
__device__ __forceinline__ unsigned short f2bf(float x){
  unsigned int u = __float_as_uint(x);
  u += 0x7fff + ((u >> 16) & 1);
  return (unsigned short)(u >> 16);
}

// ======================= device bodies ======================================

__device__ __forceinline__ void agg_body(int a, int t,
        const float* __restrict__ h_in, const int* __restrict__ nb_idx,
        const float* __restrict__ rbf, const int* __restrict__ nb_cnt,
        unsigned short* __restrict__ Af){
  int grp = t >> 6, lane = t & 63;
  __shared__ int s_j[MAXNB];
  __shared__ float s_acc[4][8][128];
  int cnt = nb_cnt[a];
  for (int idx = t; idx < cnt; idx += 256) s_j[idx] = nb_idx[a*MAXNB + idx];
  __syncthreads();
  float2 acc[8];
  #pragma unroll
  for (int k = 0; k < 8; k++) acc[k] = {0.f, 0.f};
  const float4* rb = (const float4*)(rbf + (size_t)a*MAXNB*8);
  for (int n = grp; n < cnt; n += 4){
    float2 hv = *(const float2*)&h_in[(size_t)s_j[n]*F + lane*2];
    float4 r0 = rb[n*2], r1 = rb[n*2+1];
    acc[0].x += r0.x*hv.x; acc[0].y += r0.x*hv.y;
    acc[1].x += r0.y*hv.x; acc[1].y += r0.y*hv.y;
    acc[2].x += r0.z*hv.x; acc[2].y += r0.z*hv.y;
    acc[3].x += r0.w*hv.x; acc[3].y += r0.w*hv.y;
    acc[4].x += r1.x*hv.x; acc[4].y += r1.x*hv.y;
    acc[5].x += r1.y*hv.x; acc[5].y += r1.y*hv.y;
    acc[6].x += r1.z*hv.x; acc[6].y += r1.z*hv.y;
    acc[7].x += r1.w*hv.x; acc[7].y += r1.w*hv.y;
  }
  #pragma unroll
  for (int k = 0; k < 8; k++)
    *(float2*)&s_acc[grp][k][lane*2] = acc[k];
  __syncthreads();
  int k = t >> 5, q = t & 31;
  int f0 = q*4;
  float v[4];
  #pragma unroll
  for (int i = 0; i < 4; i++){
    int f = f0 + i;
    v[i] = s_acc[0][k][f] + s_acc[1][k][f] + s_acc[2][k][f] + s_acc[3][k][f];
  }
  int lf = (a & 15) | (((f0 >> 3) & 3) << 4);
  int kc = k*4 + (f0 >> 5);
  size_t flat = (size_t)(a >> 4)*16384 + ((size_t)kc*64 + lf)*8 + (f0 & 7);
  u16x4_t o;
  o[0] = f2bf(v[0]); o[1] = f2bf(v[1]); o[2] = f2bf(v[2]); o[3] = f2bf(v[3]);
  *(u16x4_t*)(Af + flat) = o;
}

__device__ __forceinline__ void mgemm_bwd_body(int bx, int t,
        const unsigned short* __restrict__ Gf, const unsigned short* __restrict__ Bf,
        unsigned short* __restrict__ dAbf){
  int l = t & 63, w = t >> 6;
  int rtile = (bx & 63)*4 + w;
  int nt0 = (bx >> 6)*8;
  f32x4_t acc[8];
  #pragma unroll
  for (int i = 0; i < 8; i++) acc[i] = (f32x4_t){0.f,0.f,0.f,0.f};
  const unsigned short* Ab = Gf + (size_t)rtile*2048 + l*8;
  const unsigned short* Bb = Bf + l*8;
  #pragma unroll
  for (int kc = 0; kc < 4; kc++){
    bf16x8_t a = *(const bf16x8_t*)(Ab + kc*512);
    #pragma unroll
    for (int nt = 0; nt < 8; nt++){
      bf16x8_t b = *(const bf16x8_t*)(Bb + (kc*64 + nt0 + nt)*512);
      acc[nt] = __builtin_amdgcn_mfma_f32_16x16x32_bf16(a, b, acc[nt], 0, 0, 0);
    }
  }
  int row0 = rtile*16 + (l >> 4)*4;
  int col = l & 15;
  #pragma unroll
  for (int nt = 0; nt < 8; nt++){
    #pragma unroll
    for (int r = 0; r < 4; r++)
      dAbf[(size_t)(row0+r)*1024 + (nt0+nt)*16 + col] = f2bf(acc[nt][r]);
  }
}

// ======================= kernels ============================================

// ---- mega-prep: [0,1024) nb scan + rbf tail; [1024,1088) wprep; rest embed --
__global__ __launch_bounds__(256) void k_prep(const float* __restrict__ pos,
        const int* __restrict__ z, const float* __restrict__ embed,
        const float* __restrict__ W1, const float* __restrict__ W2,
        const float* __restrict__ Wr1,
        int* __restrict__ nb_idx, float* __restrict__ nb_d, int* __restrict__ nb_cnt,
        float* __restrict__ rbf, float* __restrict__ drbf,
        unsigned short* __restrict__ WF1, unsigned short* __restrict__ WF2,
        unsigned short* __restrict__ WDF2, unsigned short* __restrict__ WTF1,
        unsigned short* __restrict__ WTF2, unsigned short* __restrict__ Wr1F,
        unsigned short* __restrict__ Wr1TF,
        float* __restrict__ h0, unsigned short* __restrict__ h0bf){
  int t = threadIdx.x;
  if (blockIdx.x < 1024){
    int w = t >> 6, lane = t & 63;
    int i = blockIdx.x*4 + w;
    __shared__ float spx[256], spy[256], spz[256], ssq[256];
    float pix = pos[3*i], piy = pos[3*i+1], piz = pos[3*i+2];
    float sqi = pix*pix + piy*piy + piz*piz;
    int count = 0;
    for (int jb = 0; jb < N_ATOMS; jb += 256){
      __syncthreads();
      float px = pos[3*(jb+t)], py = pos[3*(jb+t)+1], pz = pos[3*(jb+t)+2];
      spx[t] = px; spy[t] = py; spz[t] = pz;
      ssq[t] = px*px + py*py + pz*pz;
      __syncthreads();
      #pragma unroll
      for (int c = 0; c < 4; c++){
        int jj = c*64 + lane;
        int j = jb + jj;
        float dot = pix*spx[jj] + piy*spy[jj] + piz*spz[jj];
        float d2 = sqi + ssq[jj] - 2.0f*dot;
        bool pred = (j != i) && (d2 > 0.0f) && (d2 < RMAX2);
        unsigned long long m = __ballot(pred);
        int off = __popcll(m & ((1ull << lane) - 1ull));
        if (pred){
          int p = count + off;
          if (p < MAXNB){ nb_idx[i*MAXNB + p] = j; nb_d[i*MAXNB + p] = sqrtf(d2); }
        }
        count += __popcll(m);
      }
    }
    int cc = count > MAXNB ? MAXNB : count;
    if (lane == 0) nb_cnt[i] = cc;
    __syncthreads();   // flush nb_d writes (workgroup-scope fence)
    // dense rbf/drbf tail over accepted edges only
    for (int n = lane; n < cc; n += 64){
      float d = nb_d[i*MAXNB + n];
      float ph = POR*d;
      float cph, sph;
      __sincosf(ph, &sph, &cph);
      float env = 0.5f*(cph + 1.0f);
      float denv = -0.5f*POR*sph;
      float rr[8], dd[8];
      #pragma unroll
      for (int k = 0; k < 8; k++){
        float dm = d - MU_STEP*(float)k;
        float G = expf(-GAMMA*dm*dm);
        rr[k] = G*env;
        dd[k] = G*(-2.0f*GAMMA*dm*env + denv);
      }
      float4* rb = (float4*)(rbf + ((size_t)i*MAXNB + n)*8);
      rb[0] = {rr[0],rr[1],rr[2],rr[3]};
      rb[1] = {rr[4],rr[5],rr[6],rr[7]};
      float4* db = (float4*)(drbf + ((size_t)i*MAXNB + n)*8);
      db[0] = {dd[0],dd[1],dd[2],dd[3]};
      db[1] = {dd[4],dd[5],dd[6],dd[7]};
    }
    return;
  }
  if (blockIdx.x >= 1088){
    int idx = (blockIdx.x - 1088)*256 + t;
    int i = idx >> 7, f = idx & 127;
    float v = embed[z[i]*F + f];
    h0[idx] = v;
    h0bf[idx] = f2bf(v);
    return;
  }
  int idx = (blockIdx.x - 1024)*256 + t;   // 0..16383
  int l = idx & 63;
  int hi = idx >> 6;
  {
    int kc = hi >> 3, nt = hi & 7;
    int kfb = kc*32 + ((l>>4)&3)*8;
    int g = nt*16 + (l&15);
    u16x8_t v1, v2, vd;
    #pragma unroll
    for (int j = 0; j < 8; j++){
      int kf = kfb + j;
      v1[j] = f2bf(W1[kf*128 + g]);
      v2[j] = f2bf(W2[kf*128 + g]);
      vd[j] = f2bf(W2[(kf>>7)*FF + g*F + (kf&127)]);
    }
    *(u16x8_t*)(WF1 + idx*8) = v1;
    *(u16x8_t*)(WF2 + idx*8) = v2;
    *(u16x8_t*)(WDF2 + idx*8) = vd;
  }
  {
    int kc = hi >> 6, nt = hi & 63;
    int gb = kc*32 + ((l>>4)&3)*8;
    int kf = nt*16 + (l&15);
    u16x8_t t1, t2;
    #pragma unroll
    for (int j = 0; j < 8; j++){
      int g = gb + j;
      t1[j] = f2bf(W1[kf*128 + g]);
      t2[j] = f2bf(W2[kf*128 + g]);
    }
    *(u16x8_t*)(WTF1 + idx*8) = t1;
    *(u16x8_t*)(WTF2 + idx*8) = t2;
  }
  {
    int m = idx >> 9;
    int ll = (idx >> 3) & 63;
    int j = idx & 7;
    int kc = m >> 3, nt = m & 7;
    int kf = kc*32 + ((ll>>4)&3)*8 + j;
    int g = nt*16 + (ll&15);
    Wr1F[idx]  = f2bf(Wr1[kf*128 + g]);
    Wr1TF[idx] = f2bf(Wr1[g*128 + kf]);
  }
}

// ---- standalone agg --------------------------------------------------------
__global__ __launch_bounds__(256) void k_agg(const float* __restrict__ h_in,
        const int* __restrict__ nb_idx, const float* __restrict__ rbf,
        const int* __restrict__ nb_cnt, unsigned short* __restrict__ Af){
  agg_body(blockIdx.x, threadIdx.x, h_in, nb_idx, rbf, nb_cnt, Af);
}

// ---- merged: [0,512) mgemm_bwd(dA2); [512, 4608) agg(g2) -------------------
__global__ __launch_bounds__(256) void k_bwdmix(const unsigned short* __restrict__ Gf,
        const unsigned short* __restrict__ Bf, unsigned short* __restrict__ dAbf,
        const float* __restrict__ g2b, const int* __restrict__ nb_idx,
        const float* __restrict__ rbf, const int* __restrict__ nb_cnt,
        unsigned short* __restrict__ Af){
  if (blockIdx.x < 512){
    mgemm_bwd_body(blockIdx.x, threadIdx.x, Gf, Bf, dAbf);
    return;
  }
  agg_body(blockIdx.x - 512, threadIdx.x, g2b, nb_idx, rbf, nb_cnt, Af);
}

// ---- standalone mgemm_bwd --------------------------------------------------
__global__ __launch_bounds__(256) void k_mgemm_bwd(const unsigned short* __restrict__ Gf,
        const unsigned short* __restrict__ Bf, unsigned short* __restrict__ dAbf){
  mgemm_bwd_body(blockIdx.x, threadIdx.x, Gf, Bf, dAbf);
}

// ---- full-K MFMA GEMM fwd-shape + fused epilogue ---------------------------
__global__ __launch_bounds__(256) void k_mgemm_fwd(const unsigned short* __restrict__ Af,
        const unsigned short* __restrict__ Bf, const float* __restrict__ addv,
        const float* __restrict__ msrc, float* __restrict__ out_m,
        float* __restrict__ out_h, unsigned short* __restrict__ out_hbf,
        unsigned short* __restrict__ out_frag, int mode){
  int t = threadIdx.x;
  int l = t & 63, w = t >> 6;
  int rtile = blockIdx.x;
  int nt = blockIdx.y*4 + w;
  f32x4_t accA = (f32x4_t){0.f,0.f,0.f,0.f};
  f32x4_t accB = (f32x4_t){0.f,0.f,0.f,0.f};
  const unsigned short* Ab = Af + (size_t)rtile*16384 + l*8;
  const unsigned short* Bb = Bf + l*8;
  #pragma unroll
  for (int kc = 0; kc < 32; kc += 2){
    bf16x8_t a0 = *(const bf16x8_t*)(Ab + kc*512);
    bf16x8_t b0 = *(const bf16x8_t*)(Bb + (kc*8 + nt)*512);
    bf16x8_t a1 = *(const bf16x8_t*)(Ab + (kc+1)*512);
    bf16x8_t b1 = *(const bf16x8_t*)(Bb + ((kc+1)*8 + nt)*512);
    accA = __builtin_amdgcn_mfma_f32_16x16x32_bf16(a0, b0, accA, 0, 0, 0);
    accB = __builtin_amdgcn_mfma_f32_16x16x32_bf16(a1, b1, accB, 0, 0, 0);
  }
  f32x4_t acc = accA + accB;
  int row0 = rtile*16 + (l >> 4)*4;
  int col = nt*16 + (l & 15);
  if (mode == 0){
    #pragma unroll
    for (int r = 0; r < 4; r++){
      int i = row0 + r;
      float m = acc[r] + addv[(size_t)i*F + col];
      out_m[(size_t)i*F + col] = m;
      float h = m*sigm(m);
      out_h[(size_t)i*F + col] = h;
      out_hbf[(size_t)i*F + col] = f2bf(h);
    }
  } else {
    int kc2 = col >> 5;
    int lfr0 = (((col >> 3) & 3) << 4);
    int jj = col & 7;
    #pragma unroll
    for (int r = 0; r < 4; r++){
      int i = row0 + r;
      float mm = msrc[(size_t)i*F + col];
      float sg = sigm(mm);
      float gv = (acc[r] + addv[(size_t)i*F + col])*(sg*(1.f + mm*(1.f - sg)));
      int lfr = (i & 15) | lfr0;
      size_t flat = (((size_t)(i>>4)*4 + kc2)*64 + lfr)*8 + jj;
      out_frag[flat] = f2bf(gv);
    }
  }
}

// ------- MFMA readout: 1 wave = 16 atoms ------------------------------------
__global__ __launch_bounds__(64) void k_readout(const unsigned short* __restrict__ h2bf,
        const float* __restrict__ m2, const unsigned short* __restrict__ Wr1F,
        const unsigned short* __restrict__ Wr1TF, const float* __restrict__ Wr2,
        float* __restrict__ e_at, float* __restrict__ g2,
        unsigned short* __restrict__ g2frag){
  int a0 = blockIdx.x*16;
  int l = threadIdx.x;
  int rl = l & 15;
  __shared__ unsigned short sdu[16][136];
  f32x4_t acc[8];
  #pragma unroll
  for (int nt = 0; nt < 8; nt++) acc[nt] = (f32x4_t){0.f,0.f,0.f,0.f};
  #pragma unroll
  for (int kc = 0; kc < 4; kc++){
    bf16x8_t af = *(const bf16x8_t*)(h2bf + (size_t)(a0+rl)*F + kc*32 + ((l>>4)&3)*8);
    #pragma unroll
    for (int nt = 0; nt < 8; nt++){
      bf16x8_t bf = *(const bf16x8_t*)(Wr1F + ((kc*8+nt)*64 + l)*8);
      acc[nt] = __builtin_amdgcn_mfma_f32_16x16x32_bf16(af, bf, acc[nt], 0, 0, 0);
    }
  }
  float epart[4] = {0.f,0.f,0.f,0.f};
  #pragma unroll
  for (int nt = 0; nt < 8; nt++){
    float w2 = Wr2[nt*16 + rl];
    #pragma unroll
    for (int r = 0; r < 4; r++){
      float u = acc[nt][r];
      float sg = sigm(u);
      epart[r] += u*sg*w2;
      sdu[(l>>4)*4 + r][nt*16 + rl] = f2bf(w2*(sg*(1.f + u*(1.f - sg))));
    }
  }
  #pragma unroll
  for (int o = 1; o < 16; o <<= 1){
    #pragma unroll
    for (int r = 0; r < 4; r++) epart[r] += __shfl_xor(epart[r], o);
  }
  if (rl == 0){
    #pragma unroll
    for (int r = 0; r < 4; r++) e_at[a0 + (l>>4)*4 + r] = epart[r];
  }
  __syncthreads();
  f32x4_t acc2[8];
  #pragma unroll
  for (int nt = 0; nt < 8; nt++) acc2[nt] = (f32x4_t){0.f,0.f,0.f,0.f};
  #pragma unroll
  for (int kc = 0; kc < 4; kc++){
    bf16x8_t af = *(const bf16x8_t*)&sdu[rl][kc*32 + ((l>>4)&3)*8];
    #pragma unroll
    for (int nt = 0; nt < 8; nt++){
      bf16x8_t bf = *(const bf16x8_t*)(Wr1TF + ((kc*8+nt)*64 + l)*8);
      acc2[nt] = __builtin_amdgcn_mfma_f32_16x16x32_bf16(af, bf, acc2[nt], 0, 0, 0);
    }
  }
  #pragma unroll
  for (int nt = 0; nt < 8; nt++){
    int g = nt*16 + rl;
    int kc2 = g >> 5;
    int lfr0 = (((g >> 3) & 3) << 4);
    int jj = g & 7;
    #pragma unroll
    for (int r = 0; r < 4; r++){
      int a = a0 + (l>>4)*4 + r;
      float mm = m2[(size_t)a*F + g];
      float sg = sigm(mm);
      float gv = acc2[nt][r]*(sg*(1.f + mm*(1.f - sg)));
      g2[(size_t)a*F + g] = gv;
      int lfr = (a & 15) | lfr0;
      g2frag[(((size_t)(a>>4)*4 + kc2)*64 + lfr)*8 + jj] = f2bf(gv);
    }
  }
}

// ------- per-edge scalar via MFMA -------------------------------------------
__global__ __launch_bounds__(256) void k_edge(const unsigned short* __restrict__ dA2bf,
        const unsigned short* __restrict__ dA1bf, const unsigned short* __restrict__ h1bf,
        const unsigned short* __restrict__ h0bf, const float* __restrict__ drbf,
        const int* __restrict__ nb_idx, const int* __restrict__ nb_cnt,
        float* __restrict__ edge_s){
  int a = blockIdx.x;
  int t = threadIdx.x;
  int w = t >> 6, l = t & 63;
  __shared__ int s_j[MAXNB];
  int cnt = nb_cnt[a];
  for (int idx = t; idx < cnt; idx += 256) s_j[idx] = nb_idx[a*MAXNB + idx];
  int r = l & 15;
  int sel = (l >> 4) & 3;
  u16x8_t a2u[4], a1u[4];
  #pragma unroll
  for (int kc = 0; kc < 4; kc++){
    u16x8_t v2 = {0,0,0,0,0,0,0,0};
    u16x8_t v1 = {0,0,0,0,0,0,0,0};
    if (r < 8){
      v2 = *(const u16x8_t*)(dA2bf + (size_t)a*KF + r*F + kc*32 + sel*8);
      v1 = *(const u16x8_t*)(dA1bf + (size_t)a*KF + r*F + kc*32 + sel*8);
    }
    a2u[kc] = v2; a1u[kc] = v1;
  }
  __syncthreads();
  for (int n0 = w*16; n0 < cnt; n0 += 64){
    int nl = n0 + r;
    int nls = nl < cnt ? nl : cnt - 1;
    int j = s_j[nls];
    const unsigned short* h1p = h1bf + (size_t)j*F + sel*8;
    const unsigned short* h0p = h0bf + (size_t)j*F + sel*8;
    f32x4_t acc = (f32x4_t){0.f,0.f,0.f,0.f};
    #pragma unroll
    for (int kc = 0; kc < 4; kc++){
      bf16x8_t b = *(const bf16x8_t*)(h1p + kc*32);
      acc = __builtin_amdgcn_mfma_f32_16x16x32_bf16(*(const bf16x8_t*)&a2u[kc], b, acc, 0, 0, 0);
    }
    #pragma unroll
    for (int kc = 0; kc < 4; kc++){
      bf16x8_t b = *(const bf16x8_t*)(h0p + kc*32);
      acc = __builtin_amdgcn_mfma_f32_16x16x32_bf16(*(const bf16x8_t*)&a1u[kc], b, acc, 0, 0, 0);
    }
    int krow = (l >> 4) * 4;
    float part = 0.f;
    if (krow < 8){
      float4 dr = *(const float4*)(drbf + ((size_t)a*MAXNB + nls)*8 + krow);
      part = acc[0]*dr.x + acc[1]*dr.y + acc[2]*dr.z + acc[3]*dr.w;
    }
    part += __shfl_xor(part, 16);
    if (l < 16 && nl < cnt) edge_s[a*MAXNB + nl] = part;
  }
}

// ------- force + (block N_ATOMS) energy sum ---------------------------------
__global__ __launch_bounds__(64) void k_force(const float* __restrict__ pos,
        const int* __restrict__ nb_idx, const float* __restrict__ nb_d,
        const int* __restrict__ nb_cnt, const float* __restrict__ edge_s,
        const float* __restrict__ e_at, float* __restrict__ out){
  int a = blockIdx.x;
  int lane = threadIdx.x;
  if (a == N_ATOMS){
    float s = 0.f;
    for (int i = lane; i < N_ATOMS; i += 64) s += e_at[i];
    #pragma unroll
    for (int o = 1; o < 64; o <<= 1) s += __shfl_xor(s, o);
    if (lane == 0) out[0] = s;
    return;
  }
  float pax = pos[3*a], pay = pos[3*a+1], paz = pos[3*a+2];
  int cnt = nb_cnt[a];
  float fx = 0.f, fy = 0.f, fz = 0.f;
  for (int n = lane; n < cnt; n += 64){
    int j = nb_idx[a*MAXNB + n];
    float d = nb_d[a*MAXNB + n];
    float s = edge_s[a*MAXNB + n];
    int cj = nb_cnt[j];
    int lo = 0, hi = cj - 1, p = -1;
    while (lo <= hi){
      int mid = (lo + hi) >> 1;
      int v = nb_idx[j*MAXNB + mid];
      if (v == a){ p = mid; break; }
      if (v < a) lo = mid + 1; else hi = mid - 1;
    }
    float sj = (p >= 0) ? edge_s[j*MAXNB + p] : 0.0f;
    float coef = (s + sj)/d;
    float dx = pax - pos[3*j], dy = pay - pos[3*j+1], dz = paz - pos[3*j+2];
    fx -= coef*dx; fy -= coef*dy; fz -= coef*dz;
  }
  #pragma unroll
  for (int o = 1; o < 64; o <<= 1){
    fx += __shfl_xor(fx, o); fy += __shfl_xor(fy, o); fz += __shfl_xor(fz, o);
  }
  if (lane == 0){
    out[1 + 3*a + 0] = fx;
    out[1 + 3*a + 1] = fy;
    out[1 + 3*a + 2] = fz;
  }
}

extern "C" void kernel_launch(void* const* d_in, const int* in_sizes, int n_in,
                              void* d_out, int out_size, void* d_ws, size_t ws_size,
                              hipStream_t stream){
  const float* pos   = (const float*)d_in[0];
  const int*   z     = (const int*)  d_in[1];
  const float* embed = (const float*)d_in[2];
  const float* W1    = (const float*)d_in[3];
  const float* W2    = (const float*)d_in[4];
  const float* Wr1   = (const float*)d_in[5];
  const float* Wr2   = (const float*)d_in[6];
  float* out = (float*)d_out;

  float* ws = (float*)d_ws;
  float* h0   = ws;            // NF
  float* h1   = h0 + NF;
  float* h2   = h1 + NF;
  float* m1   = h2 + NF;
  float* m2   = m1 + NF;
  float* g2b  = m2 + NF;
  float* Bbuf = g2b + NF;      // NKF slot: dA2 bf16
  float* Cbuf = Bbuf + NKF;    // NKF slot: dA1 bf16
  unsigned short* dA2bf = (unsigned short*)Bbuf;
  unsigned short* dA1bf = (unsigned short*)Cbuf;
  unsigned short* Afrag = (unsigned short*)(Cbuf + NKF);  // NKF bf16
  unsigned short* Gfrag = Afrag + NKF;                    // NF bf16
  unsigned short* h0bf = Gfrag + NF;   // NF bf16
  unsigned short* h1bf = h0bf + NF;    // NF bf16
  unsigned short* h2bf = h1bf + NF;    // NF bf16
  unsigned short* WF1  = h2bf + NF;    // KFF bf16 each
  unsigned short* WF2  = WF1 + KFF;
  unsigned short* WDF2 = WF2 + KFF;
  unsigned short* WTF1 = WDF2 + KFF;
  unsigned short* WTF2 = WTF1 + KFF;
  unsigned short* Wr1F  = WTF2 + KFF;  // FF bf16
  unsigned short* Wr1TF = Wr1F + FF;   // FF bf16
  float* e_at = (float*)(Wr1TF + FF);  // N
  float* nb_d = e_at + N_ATOMS;        // N*MAXNB
  float* edge_s = nb_d + N_ATOMS*MAXNB;// N*MAXNB
  float* rbf  = edge_s + N_ATOMS*MAXNB;         // N*MAXNB*8
  float* drbf = rbf + N_ATOMS*MAXNB*8;          // N*MAXNB*8
  int* nb_idx = (int*)(drbf + N_ATOMS*MAXNB*8); // N*MAXNB
  int* nb_cnt = nb_idx + N_ATOMS*MAXNB;         // N

  // prep: nb+rbf (1024) | wprep (64) | embed (2048)
  k_prep<<<1024 + 64 + NF/256, 256, 0, stream>>>(pos, z, embed, W1, W2, Wr1,
        nb_idx, nb_d, nb_cnt, rbf, drbf,
        WF1, WF2, WDF2, WTF1, WTF2, Wr1F, Wr1TF, h0, h0bf);

  // forward layer 1
  k_agg<<<N_ATOMS, 256, 0, stream>>>(h0, nb_idx, rbf, nb_cnt, Afrag);
  k_mgemm_fwd<<<dim3(256, 2), 256, 0, stream>>>(Afrag, WF1, h0, h0, m1, h1, h1bf, Gfrag, 0);
  // forward layer 2
  k_agg<<<N_ATOMS, 256, 0, stream>>>(h1, nb_idx, rbf, nb_cnt, Afrag);
  k_mgemm_fwd<<<dim3(256, 2), 256, 0, stream>>>(Afrag, WF2, h1, h1, m2, h2, h2bf, Gfrag, 0);

  // MFMA readout (writes e_at, g2 f32 + frag)
  k_readout<<<N_ATOMS/16, 64, 0, stream>>>(h2bf, m2, Wr1F, Wr1TF, Wr2, e_at, g2b, Gfrag);

  // backward: dA2 GEMM + Agg2 in one launch
  k_bwdmix<<<512 + N_ATOMS, 256, 0, stream>>>(Gfrag, WTF2, dA2bf,
        g2b, nb_idx, rbf, nb_cnt, Afrag);
  k_mgemm_fwd<<<dim3(256, 2), 256, 0, stream>>>(Afrag, WDF2, g2b, m1, m1, m1, h2bf, Gfrag, 1); // g1 -> Gfrag
  k_mgemm_bwd<<<512, 256, 0, stream>>>(Gfrag, WTF1, dA1bf);       // dA1
  k_edge<<<N_ATOMS, 256, 0, stream>>>(dA2bf, dA1bf, h1bf, h0bf, drbf, nb_idx, nb_cnt, edge_s);
  k_force<<<N_ATOMS + 1, 64, 0, stream>>>(pos, nb_idx, nb_d, nb_cnt, edge_s, e_at, out);
}